// Round 12
// baseline (1299.341 us; speedup 1.0000x reference)
//
#include <hip/hip_runtime.h>
#include <hip/hip_bf16.h>

// Problem constants
#define Bz 16
#define Tz 32
#define Sz 128
#define TPz 4
#define Mz (Bz*Sz)          // 2048 rows
#define NSTEP (Tz-1)        // 31

typedef __bf16 bf16x8 __attribute__((ext_vector_type(8)));
typedef float  f32x4  __attribute__((ext_vector_type(4)));

#define MFMA __builtin_amdgcn_mfma_f32_16x16x32_bf16

__device__ __forceinline__ float sigf(float x) { return 1.f/(1.f + __expf(-x)); }
// fast tanh: 1 - 2/(e^{2x}+1); exact at +-inf, ~1e-7 rel err, v_exp+rcp only
__device__ __forceinline__ float tanhfast(float x) { return 1.f - 2.f/(__expf(2.f*x) + 1.f); }

// ---------------------------------------------------------------------------
// prep3 (verified rounds 7/8/10/11): pack weights (fp32) into bf16 MFMA
// B-fragment order: P[((nt*KT + kt)*64 + lane)*8 + j] =
//        BT[nt*16 + (lane&15)][kt*32 + (lane>>4)*8 + j]
// ---------------------------------------------------------------------------
__global__ __launch_bounds__(256) void prep3(
    const float* __restrict__ encWq, const float* __restrict__ encWk,
    const float* __restrict__ encWv, const float* __restrict__ encWg,
    const float* __restrict__ decWq, const float* __restrict__ decWk,
    const float* __restrict__ decWv, const float* __restrict__ decWg,
    const float* __restrict__ embW,
    __bf16* __restrict__ Pqkv_e, __bf16* __restrict__ Pqkv_d,
    __bf16* __restrict__ Pemb,   __bf16* __restrict__ Pg_e,
    __bf16* __restrict__ Pg_d)
{
    int id = blockIdx.x * 256 + threadIdx.x;
    if (id < 768*256) {
        int f = id >> 9, e = id & 511, l = e >> 3, j = e & 7;
        int nt = f >> 3, kt = f & 7;
        int n = nt*16 + (l & 15), k = kt*32 + (l >> 4)*8 + j;
        float v = (n < 256) ? encWq[k*256 + n]
                : (n < 512) ? encWk[k*256 + (n-256)]
                            : encWv[k*256 + (n-512)];
        Pqkv_e[id] = (__bf16)v; return;
    }
    id -= 768*256;
    if (id < 768*256) {
        int f = id >> 9, e = id & 511, l = e >> 3, j = e & 7;
        int nt = f >> 3, kt = f & 7;
        int n = nt*16 + (l & 15), k = kt*32 + (l >> 4)*8 + j;
        float v = (n < 256) ? decWq[k*256 + n]
                : (n < 512) ? decWk[k*256 + (n-256)]
                            : decWv[k*256 + (n-512)];
        Pqkv_d[id] = (__bf16)v; return;
    }
    id -= 768*256;
    if (id < 256*256) {
        int f = id >> 9, e = id & 511, l = e >> 3, j = e & 7;
        int nt = f >> 3, kt = f & 7;
        int n = nt*16 + (l & 15), k = kt*32 + (l >> 4)*8 + j;
        Pemb[id] = (__bf16)embW[k*256 + n]; return;
    }
    id -= 256*256;
    if (id < 1024*512) {
        int f = id >> 9, e = id & 511, l = e >> 3, j = e & 7;
        int nt = f >> 4, kt = f & 15;
        int cht = nt >> 2, g = nt & 3;
        int ch = cht*16 + (l & 15), k = kt*32 + (l >> 4)*8 + j;
        Pg_e[id] = (__bf16)encWg[(size_t)(3 + k)*1024 + g*256 + ch]; return;
    }
    id -= 1024*512;
    if (id < 1024*768) {
        int f = id >> 9, e = id & 511, l = e >> 3, j = e & 7;
        int nt = f / 24, kt = f % 24;
        int cht = nt >> 2, g = nt & 3;
        int ch = cht*16 + (l & 15), k = kt*32 + (l >> 4)*8 + j;
        Pg_d[id] = (__bf16)decWg[(size_t)k*1024 + g*256 + ch]; return;
    }
}

// ---------------------------------------------------------------------------
// qkv GEMM from 36-row staged state (stride 264) -> qL (own 32 rows), kvL (36).
// (verified rounds 7/8/10/11)
// ---------------------------------------------------------------------------
__device__ __forceinline__ void qkv_lds(
    const __bf16* src264, const __bf16* __restrict__ P,
    __bf16* qL, __bf16* kvL, int tid)
{
    const int w = tid >> 6, lane = tid & 63, quad = (lane >> 4), lr = lane & 15;
    #pragma unroll
    for (int ng = 0; ng < 3; ++ng) {
        const int ntA = w*6 + ng*2;
        f32x4 acc[2][3];
        #pragma unroll
        for (int i = 0; i < 2; ++i)
            #pragma unroll
            for (int m = 0; m < 3; ++m) acc[i][m] = f32x4{0.f,0.f,0.f,0.f};
        for (int kt = 0; kt < 8; ++kt) {
            bf16x8 a0 = *(const bf16x8*)&src264[(lr)*264      + kt*32 + quad*8];
            bf16x8 a1 = *(const bf16x8*)&src264[(16 + lr)*264 + kt*32 + quad*8];
            bf16x8 a2 = *(const bf16x8*)&src264[(32 + lr)*264 + kt*32 + quad*8];
            bf16x8 b0 = *(const bf16x8*)&P[((size_t)(ntA*8 + kt)*64 + lane)*8];
            bf16x8 b1 = *(const bf16x8*)&P[((size_t)((ntA+1)*8 + kt)*64 + lane)*8];
            acc[0][0] = MFMA(a0, b0, acc[0][0], 0,0,0);
            acc[0][1] = MFMA(a1, b0, acc[0][1], 0,0,0);
            acc[0][2] = MFMA(a2, b0, acc[0][2], 0,0,0);
            acc[1][0] = MFMA(a0, b1, acc[1][0], 0,0,0);
            acc[1][1] = MFMA(a1, b1, acc[1][1], 0,0,0);
            acc[1][2] = MFMA(a2, b1, acc[1][2], 0,0,0);
        }
        #pragma unroll
        for (int i = 0; i < 2; ++i) {
            const int col = (ntA + i)*16 + lr;
            #pragma unroll
            for (int m = 0; m < 3; ++m)
                #pragma unroll
                for (int r = 0; r < 4; ++r) {
                    const int row = m*16 + quad*4 + r;
                    const float v = acc[i][m][r];
                    if (col < 256) {
                        if (row >= 2 && row < 34) qL[(row-2)*264 + col] = (__bf16)v;
                    } else if (row < 36) {
                        kvL[row*520 + (col - 256)] = (__bf16)v;
                    }
                }
        }
    }
}

// ---------------------------------------------------------------------------
// Attention (32 rows) from LDS qL/kvL -> cxL. (verified rounds 7/8/10/11)
// cxL MAY alias qL: each lane reads only the q chunk it later overwrites.
// ---------------------------------------------------------------------------
__device__ __forceinline__ void attn_lds(
    const __bf16* qL, const __bf16* kvL, __bf16* cxL, int s0, int tid)
{
    const int w = tid >> 6, lane = tid & 63, quad = lane >> 4, lr = lane & 15;
    const int r = 4*w + quad, s = s0 + r, ch0 = lr*16;

    float q[16];
    {
        bf16x8 q0 = *(const bf16x8*)&qL[r*264 + ch0];
        bf16x8 q1 = *(const bf16x8*)&qL[r*264 + ch0 + 8];
        #pragma unroll
        for (int i = 0; i < 8; ++i) { q[i] = (float)q0[i]; q[8+i] = (float)q1[i]; }
    }
    bf16x8 zv;
    #pragma unroll
    for (int i = 0; i < 8; ++i) zv[i] = (__bf16)0.f;

    const int offs[4] = {2, 1, -1, -2};
    float sc[4]; bf16x8 v0[4], v1[4];
    #pragma unroll
    for (int n = 0; n < 4; ++n) {
        const int s2 = s + offs[n];
        const bool ok = ((unsigned)s2 < 128u);
        const int lrow = r + offs[n] + 2;
        float p = 0.f;
        if (ok) {
            bf16x8 k0 = *(const bf16x8*)&kvL[lrow*520 + ch0];
            bf16x8 k1 = *(const bf16x8*)&kvL[lrow*520 + ch0 + 8];
            v0[n] = *(const bf16x8*)&kvL[lrow*520 + 256 + ch0];
            v1[n] = *(const bf16x8*)&kvL[lrow*520 + 256 + ch0 + 8];
            #pragma unroll
            for (int i = 0; i < 8; ++i) p += q[i]*(float)k0[i] + q[8+i]*(float)k1[i];
        } else { v0[n] = zv; v1[n] = zv; }
        p += __shfl_xor(p, 1);
        sc[n] = ok ? p * 0.17677669529663687f : 0.f;
    }
    const float mx = fmaxf(fmaxf(sc[0], sc[1]), fmaxf(sc[2], sc[3]));
    float se = 0.f, aw[4];
    #pragma unroll
    for (int n = 0; n < 4; ++n) { aw[n] = __expf(sc[n] - mx); se += aw[n]; }
    const float inv = 1.f / se;
    float cx[16];
    #pragma unroll
    for (int i = 0; i < 16; ++i) cx[i] = 0.f;
    #pragma unroll
    for (int n = 0; n < 4; ++n)
        #pragma unroll
        for (int i = 0; i < 8; ++i) {
            cx[i]   += aw[n]*(float)v0[n][i];
            cx[8+i] += aw[n]*(float)v1[n][i];
        }
    bf16x8 o0, o1;
    #pragma unroll
    for (int i = 0; i < 8; ++i) { o0[i] = (__bf16)(cx[i]*inv); o1[i] = (__bf16)(cx[8+i]*inv); }
    *(bf16x8*)&cxL[r*264 + ch0]     = o0;
    *(bf16x8*)&cxL[r*264 + ch0 + 8] = o1;
}

// ---------------------------------------------------------------------------
// step_k: ONE dispatch per scan step k (k = 0..NSTEP).
// blocks 0..255  : dec step td = k-1 (skip if k==0)
// blocks 256..511: enc step te = k   (skip if k==NSTEP)
// LDS arena 73856 B -> 2 blocks/CU co-resident. Layout as round 11 (verified).
// ---------------------------------------------------------------------------
#define SM_A264   0
#define SM_R      19008
#define SM_CODE   35904
#define SM_Q      56448
#define SM_MISC   73344
#define SM_TOTAL  73856

__global__ __launch_bounds__(512, 4) void step_k(
    int k, const float* __restrict__ input,
    __bf16* __restrict__ P, __bf16* __restrict__ Q,
    const __bf16* __restrict__ Pqkv_e, const __bf16* __restrict__ Pqkv_d,
    const __bf16* __restrict__ Pemb,   const __bf16* __restrict__ Pg_e,
    const __bf16* __restrict__ Pg_d,
    const float* __restrict__ encWg, const float* __restrict__ encbg,
    const float* __restrict__ decbg, const float* __restrict__ embb,
    const float* __restrict__ outW,
    float* __restrict__ ec, float* __restrict__ outbuf)
{
    __shared__ __attribute__((aligned(16))) char SM[SM_TOTAL];

    const int tid  = threadIdx.x;
    const int w    = tid >> 6;
    const int lane = tid & 63;
    const int quad = lane >> 4, lr = lane & 15;
    const int mt = w >> 2, ct = w & 3;

    __bf16* aL  = (__bf16*)(SM + SM_A264);   // hL / dhL
    __bf16* kvL = (__bf16*)(SM + SM_R);
    __bf16* qL  = (__bf16*)(SM + SM_Q);
    __bf16* cxL = qL;                        // alias (safe, see attn_lds)

    if (blockIdx.x >= 256) {
        // ===================== ENC body (step te = k) =====================
        if (k >= NSTEP) return;
        const int bid = blockIdx.x - 256;
        const int b = bid >> 4, rg = (bid >> 2) & 3, qt = bid & 3;
        const int gbatch = b*128, s0 = rg*32, grow0 = gbatch + s0;
        const int ch = qt*64 + ct*16 + lr;
        float* xL = (float*)(SM + SM_MISC);

        // per-lane LSTM constants loaded early (before any barrier)
        float wx0[4], wx1[4], wx2[4], bgv[4];
        #pragma unroll
        for (int g = 0; g < 4; ++g) {
            const int c = g*256 + ch;
            wx0[g] = encWg[c]; wx1[g] = encWg[1024 + c]; wx2[g] = encWg[2048 + c];
            bgv[g] = encbg[c];
        }

        // stage eh_{k-1} halo rows (s0-2 .. s0+33) from P.enc
        for (int v = tid; v < 36*32; v += 512) {
            const int row = v >> 5, seg = v & 31, s = s0 - 2 + row;
            bf16x8 val;
            if ((unsigned)s < 128u)
                val = *(const bf16x8*)&P[(size_t)(gbatch + s)*512 + seg*8];
            else {
                #pragma unroll
                for (int i = 0; i < 8; ++i) val[i] = (__bf16)0.f;
            }
            *(bf16x8*)&aL[row*264 + seg*8] = val;
        }
        if (tid < 96) xL[tid] = input[((size_t)(b*Tz + k)*Sz + s0)*3 + tid];
        __syncthreads();

        qkv_lds(aL, Pqkv_e, qL, kvL, tid);
        __syncthreads();
        attn_lds(qL, kvL, cxL, s0, tid);
        __syncthreads();

        // gates (K=512: aL own rows | cxL) + LSTM
        f32x4 acc[4];
        #pragma unroll
        for (int g = 0; g < 4; ++g) acc[g] = f32x4{0.f,0.f,0.f,0.f};
        for (int kt = 0; kt < 16; ++kt) {
            const __bf16* As = (kt < 8)
                ? &aL [(2 + mt*16 + lr)*264 + kt*32 + quad*8]
                : &cxL[(mt*16 + lr)*264 + (kt-8)*32 + quad*8];
            bf16x8 af = *(const bf16x8*)As;
            #pragma unroll
            for (int g = 0; g < 4; ++g) {
                const int nt = qt*16 + ct*4 + g;
                bf16x8 bf = *(const bf16x8*)&Pg_e[((size_t)(nt*16 + kt)*64 + lane)*8];
                acc[g] = MFMA(af, bf, acc[g], 0,0,0);
            }
        }
        #pragma unroll
        for (int r = 0; r < 4; ++r) {
            const int row = mt*16 + quad*4 + r;
            const float x0 = xL[row*3], x1 = xL[row*3+1], x2 = xL[row*3+2];
            const float zi = acc[0][r] + x0*wx0[0] + x1*wx1[0] + x2*wx2[0] + bgv[0];
            const float zf = acc[1][r] + x0*wx0[1] + x1*wx1[1] + x2*wx2[1] + bgv[1];
            const float zg = acc[2][r] + x0*wx0[2] + x1*wx1[2] + x2*wx2[2] + bgv[2];
            const float zo = acc[3][r] + x0*wx0[3] + x1*wx1[3] + x2*wx2[3] + bgv[3];
            const size_t ei = (size_t)(grow0 + row)*256 + ch;
            const float cn = sigf(zf)*ec[ei] + sigf(zi)*tanhfast(zg);
            ec[ei] = cn;
            Q[(size_t)(grow0 + row)*512 + ch] = (__bf16)(sigf(zo)*tanhfast(cn));
        }
    } else {
        // ===================== DEC body (step td = k-1) =====================
        if (k < 1) return;
        const int td = k - 1;
        const int bid = blockIdx.x;
        const int b = bid >> 4, rg = (bid >> 2) & 3, qt = bid & 3;
        const int gbatch = b*128, s0 = rg*32, grow0 = gbatch + s0;
        const int ch = qt*64 + ct*16 + lr;
        __bf16* dhL   = aL;
        __bf16* ehtL  = (__bf16*)(SM + SM_R);      // dead after code GEMM
        __bf16* codeL = (__bf16*)(SM + SM_CODE);   // dead after gates code-part
        float* outredL = (float*)(SM + SM_MISC);

        // per-lane constants early
        float bgv[4];
        #pragma unroll
        for (int g = 0; g < 4; ++g) bgv[g] = decbg[g*256 + ch];
        const float ow = outW[ch];

        // stage eh_{td} own rows (P.enc) + dh_{td-1} halo (Q.dh)
        for (int v = tid; v < 32*32; v += 512) {
            const int row = v >> 5, seg = v & 31;
            *(bf16x8*)&ehtL[row*264 + seg*8] =
                *(const bf16x8*)&P[(size_t)(grow0 + row)*512 + seg*8];
        }
        for (int v = tid; v < 36*32; v += 512) {
            const int row = v >> 5, seg = v & 31, s = s0 - 2 + row;
            bf16x8 val;
            if ((unsigned)s < 128u)
                val = *(const bf16x8*)&Q[(size_t)(gbatch + s)*512 + 256 + seg*8];
            else {
                #pragma unroll
                for (int i = 0; i < 8; ++i) val[i] = (__bf16)0.f;
            }
            *(bf16x8*)&dhL[row*264 + seg*8] = val;
        }
        __syncthreads();

        // code = sig(eh_{td} @ embW + embb) -> codeL
        // (ehtL reads and codeL writes are DISJOINT LDS regions -> no extra sync)
        {
            f32x4 cacc[2][2];
            #pragma unroll
            for (int m = 0; m < 2; ++m)
                #pragma unroll
                for (int i = 0; i < 2; ++i) cacc[m][i] = f32x4{0.f,0.f,0.f,0.f};
            for (int kt = 0; kt < 8; ++kt) {
                bf16x8 a0 = *(const bf16x8*)&ehtL[(lr)*264      + kt*32 + quad*8];
                bf16x8 a1 = *(const bf16x8*)&ehtL[(16 + lr)*264 + kt*32 + quad*8];
                #pragma unroll
                for (int i = 0; i < 2; ++i) {
                    bf16x8 bf = *(const bf16x8*)&Pemb[((size_t)((2*w + i)*8 + kt)*64 + lane)*8];
                    cacc[0][i] = MFMA(a0, bf, cacc[0][i], 0,0,0);
                    cacc[1][i] = MFMA(a1, bf, cacc[1][i], 0,0,0);
                }
            }
            #pragma unroll
            for (int i = 0; i < 2; ++i) {
                const int col = (2*w + i)*16 + lr;
                const float bb = embb[col];
                #pragma unroll
                for (int m = 0; m < 2; ++m)
                    #pragma unroll
                    for (int r = 0; r < 4; ++r)
                        codeL[(m*16 + quad*4 + r)*264 + col] = (__bf16)sigf(cacc[m][i][r] + bb);
            }
        }
        __syncthreads();   // codeL visible to all waves

        // gates acc: code part FIRST (kt 0..7) so codeL dies before kvL overlay
        f32x4 acc[4];
        #pragma unroll
        for (int g = 0; g < 4; ++g) acc[g] = f32x4{0.f,0.f,0.f,0.f};
        for (int kt = 0; kt < 8; ++kt) {
            bf16x8 af = *(const bf16x8*)&codeL[(mt*16 + lr)*264 + kt*32 + quad*8];
            #pragma unroll
            for (int g = 0; g < 4; ++g) {
                const int nt = qt*16 + ct*4 + g;
                bf16x8 bf = *(const bf16x8*)&Pg_d[((size_t)(nt*24 + kt)*64 + lane)*8];
                acc[g] = MFMA(af, bf, acc[g], 0,0,0);
            }
        }
        __syncthreads();   // codeL/ehtL dead; kvL may now overwrite region R

        // dec qkv from dh_{td-1} halo (kvL overlays ehtL+codeL region)
        qkv_lds(dhL, Pqkv_d, qL, kvL, tid);
        __syncthreads();
        attn_lds(qL, kvL, cxL, s0, tid);
        __syncthreads();

        // gates rest (kt 8..23: dhL own | cxL) + LSTM + outproj
        for (int kt = 8; kt < 24; ++kt) {
            const __bf16* As = (kt < 16)
                ? &dhL[(2 + mt*16 + lr)*264 + (kt-8)*32 + quad*8]
                : &cxL[(mt*16 + lr)*264 + (kt-16)*32 + quad*8];
            bf16x8 af = *(const bf16x8*)As;
            #pragma unroll
            for (int g = 0; g < 4; ++g) {
                const int nt = qt*16 + ct*4 + g;
                bf16x8 bf = *(const bf16x8*)&Pg_d[((size_t)(nt*24 + kt)*64 + lane)*8];
                acc[g] = MFMA(af, bf, acc[g], 0,0,0);
            }
        }
        #pragma unroll
        for (int r = 0; r < 4; ++r) {
            const int row = mt*16 + quad*4 + r;
            const float zi = acc[0][r] + bgv[0];
            const float zf = acc[1][r] + bgv[1];
            const float zg = acc[2][r] + bgv[2];
            const float zo = acc[3][r] + bgv[3];
            const float c_old = (float)dhL[(2 + row)*264 + ch];
            const float cn = sigf(zf)*c_old + sigf(zi)*tanhfast(zg);
            const float h  = sigf(zo)*tanhfast(cn);
            P[(size_t)(grow0 + row)*512 + 256 + ch] = (__bf16)h;
            float pv = h * ow;
            pv += __shfl_xor(pv, 1); pv += __shfl_xor(pv, 2);
            pv += __shfl_xor(pv, 4); pv += __shfl_xor(pv, 8);
            if (lr == 0) outredL[row*4 + ct] = pv;
        }
        __syncthreads();
        if (tid < 32) {
            const float s4 = outredL[tid*4] + outredL[tid*4+1]
                           + outredL[tid*4+2] + outredL[tid*4+3];
            atomicAdd(&outbuf[(size_t)td*Mz + grow0 + tid], s4);
        }
    }
}

// ---------------------------------------------------------------------------
// Final assembly (unchanged, verified)
// ---------------------------------------------------------------------------
__global__ __launch_bounds__(256) void assemble_k(
    const float* __restrict__ outbuf, const float* __restrict__ input,
    const float* __restrict__ outb, float* __restrict__ out)
{
    const int idx = blockIdx.x*256 + threadIdx.x;
    const int NT = NSTEP - TPz;                 // 27
    if (idx >= Bz*NT*Sz) return;
    const int s  = idx & 127;
    const int bi = idx >> 7;
    const int i  = bi % NT;
    const int b  = bi / NT;
    const int t  = i + TPz;
    const float ob = outb[0];
    const float o  = outbuf[t*Mz + (b<<7) + s] + ob;
    const float In = (s == 0)
        ? input[((size_t)(b*Tz + t + 1)*Sz)*3 + 1]
        : outbuf[t*Mz + (b<<7) + s - 1] + ob;
    const float num = input[((size_t)(b*Tz + t)*Sz + s)*3 + 2] + In - o;
    const size_t base = ((size_t)(b*NT + i)*Sz + s)*3;
    out[base+0] = o;
    out[base+1] = In;
    out[base+2] = num;
}

// ---------------------------------------------------------------------------
extern "C" void kernel_launch(void* const* d_in, const int* in_sizes, int n_in,
                              void* d_out, int out_size, void* d_ws, size_t ws_size,
                              hipStream_t stream)
{
    const float* input = (const float*)d_in[0];
    const float* encWq = (const float*)d_in[1];
    const float* encWk = (const float*)d_in[2];
    const float* encWv = (const float*)d_in[3];
    const float* encWg = (const float*)d_in[4];
    const float* encbg = (const float*)d_in[5];
    const float* decWq = (const float*)d_in[6];
    const float* decWk = (const float*)d_in[7];
    const float* decWv = (const float*)d_in[8];
    const float* decWg = (const float*)d_in[9];
    const float* decbg = (const float*)d_in[10];
    const float* embW  = (const float*)d_in[11];
    const float* embb  = (const float*)d_in[12];
    const float* outW  = (const float*)d_in[13];
    const float* outb  = (const float*)d_in[14];

    char* ws = (char*)d_ws;
    size_t off = 0;
    auto alloc = [&](size_t bytes) -> void* {
        void* p = ws + off;
        off += (bytes + 255) & ~(size_t)255;
        return p;
    };
    __bf16* Pqkv_e = (__bf16*)alloc((size_t)768*256*2);
    __bf16* Pqkv_d = (__bf16*)alloc((size_t)768*256*2);
    __bf16* Pemb   = (__bf16*)alloc((size_t)256*256*2);
    __bf16* Pg_e   = (__bf16*)alloc((size_t)1024*512*2);
    __bf16* Pg_d   = (__bf16*)alloc((size_t)1024*768*2);
    __bf16* Xa     = (__bf16*)alloc((size_t)Mz*512*2);   // [ehb|dh] ping
    __bf16* Xb     = (__bf16*)alloc((size_t)Mz*512*2);   // pong
    float*  ec     = (float*) alloc((size_t)Mz*256*4);
    float*  outbuf = (float*) alloc((size_t)NSTEP*Mz*4);

    hipMemsetAsync(Xa, 0, (size_t)Mz*512*2, stream);
    hipMemsetAsync(ec, 0, (size_t)Mz*256*4, stream);
    hipMemsetAsync(outbuf, 0, (size_t)NSTEP*Mz*4, stream);

    prep3<<<6912, 256, 0, stream>>>(encWq, encWk, encWv, encWg,
                                    decWq, decWk, decWv, decWg, embW,
                                    Pqkv_e, Pqkv_d, Pemb, Pg_e, Pg_d);

    for (int k = 0; k <= NSTEP; ++k) {
        __bf16* P = (k & 1) ? Xb : Xa;
        __bf16* Q = (k & 1) ? Xa : Xb;
        step_k<<<512, 512, 0, stream>>>(k, input, P, Q,
                                        Pqkv_e, Pqkv_d, Pemb, Pg_e, Pg_d,
                                        encWg, encbg, decbg, embb, outW,
                                        ec, outbuf);
    }
    assemble_k<<<(Bz*(NSTEP-TPz)*Sz + 255)/256, 256, 0, stream>>>(
        outbuf, input, outb, (float*)d_out);
}

// Round 13
// 1294.270 us; speedup vs baseline: 1.0039x; 1.0039x over previous
//
#include <hip/hip_runtime.h>
#include <hip/hip_bf16.h>

// Problem constants
#define Bz 16
#define Tz 32
#define Sz 128
#define TPz 4
#define Mz (Bz*Sz)          // 2048 rows
#define NSTEP (Tz-1)        // 31

typedef __bf16 bf16x8 __attribute__((ext_vector_type(8)));
typedef float  f32x4  __attribute__((ext_vector_type(4)));

#define MFMA __builtin_amdgcn_mfma_f32_16x16x32_bf16

__device__ __forceinline__ float sigf(float x) { return 1.f/(1.f + __expf(-x)); }
// fast tanh: 1 - 2/(e^{2x}+1); exact at +-inf, ~1e-7 rel err
__device__ __forceinline__ float tanhfast(float x) { return 1.f - 2.f/(__expf(2.f*x) + 1.f); }

// ---------------------------------------------------------------------------
// prep3 (verified rounds 7/8/10/11/12): pack weights (fp32) into bf16 MFMA
// B-fragment order: P[((nt*KT + kt)*64 + lane)*8 + j] =
//        BT[nt*16 + (lane&15)][kt*32 + (lane>>4)*8 + j]
// ---------------------------------------------------------------------------
__global__ __launch_bounds__(256) void prep3(
    const float* __restrict__ encWq, const float* __restrict__ encWk,
    const float* __restrict__ encWv, const float* __restrict__ encWg,
    const float* __restrict__ decWq, const float* __restrict__ decWk,
    const float* __restrict__ decWv, const float* __restrict__ decWg,
    const float* __restrict__ embW,
    __bf16* __restrict__ Pqkv_e, __bf16* __restrict__ Pqkv_d,
    __bf16* __restrict__ Pemb,   __bf16* __restrict__ Pg_e,
    __bf16* __restrict__ Pg_d)
{
    int id = blockIdx.x * 256 + threadIdx.x;
    if (id < 768*256) {
        int f = id >> 9, e = id & 511, l = e >> 3, j = e & 7;
        int nt = f >> 3, kt = f & 7;
        int n = nt*16 + (l & 15), k = kt*32 + (l >> 4)*8 + j;
        float v = (n < 256) ? encWq[k*256 + n]
                : (n < 512) ? encWk[k*256 + (n-256)]
                            : encWv[k*256 + (n-512)];
        Pqkv_e[id] = (__bf16)v; return;
    }
    id -= 768*256;
    if (id < 768*256) {
        int f = id >> 9, e = id & 511, l = e >> 3, j = e & 7;
        int nt = f >> 3, kt = f & 7;
        int n = nt*16 + (l & 15), k = kt*32 + (l >> 4)*8 + j;
        float v = (n < 256) ? decWq[k*256 + n]
                : (n < 512) ? decWk[k*256 + (n-256)]
                            : decWv[k*256 + (n-512)];
        Pqkv_d[id] = (__bf16)v; return;
    }
    id -= 768*256;
    if (id < 256*256) {
        int f = id >> 9, e = id & 511, l = e >> 3, j = e & 7;
        int nt = f >> 3, kt = f & 7;
        int n = nt*16 + (l & 15), k = kt*32 + (l >> 4)*8 + j;
        Pemb[id] = (__bf16)embW[k*256 + n]; return;
    }
    id -= 256*256;
    if (id < 1024*512) {
        int f = id >> 9, e = id & 511, l = e >> 3, j = e & 7;
        int nt = f >> 4, kt = f & 15;
        int cht = nt >> 2, g = nt & 3;
        int ch = cht*16 + (l & 15), k = kt*32 + (l >> 4)*8 + j;
        Pg_e[id] = (__bf16)encWg[(size_t)(3 + k)*1024 + g*256 + ch]; return;
    }
    id -= 1024*512;
    if (id < 1024*768) {
        int f = id >> 9, e = id & 511, l = e >> 3, j = e & 7;
        int nt = f / 24, kt = f % 24;
        int cht = nt >> 2, g = nt & 3;
        int ch = cht*16 + (l & 15), k = kt*32 + (l >> 4)*8 + j;
        Pg_d[id] = (__bf16)decWg[(size_t)k*1024 + g*256 + ch]; return;
    }
}

// ---------------------------------------------------------------------------
// qkv GEMM from 36-row staged state (stride 264) -> qL (own 32 rows), kvL (36).
// (verified rounds 7/8/10/11/12)
// ---------------------------------------------------------------------------
__device__ __forceinline__ void qkv_lds(
    const __bf16* src264, const __bf16* __restrict__ P,
    __bf16* qL, __bf16* kvL, int tid)
{
    const int w = tid >> 6, lane = tid & 63, quad = (lane >> 4), lr = lane & 15;
    #pragma unroll
    for (int ng = 0; ng < 3; ++ng) {
        const int ntA = w*6 + ng*2;
        f32x4 acc[2][3];
        #pragma unroll
        for (int i = 0; i < 2; ++i)
            #pragma unroll
            for (int m = 0; m < 3; ++m) acc[i][m] = f32x4{0.f,0.f,0.f,0.f};
        for (int kt = 0; kt < 8; ++kt) {
            bf16x8 a0 = *(const bf16x8*)&src264[(lr)*264      + kt*32 + quad*8];
            bf16x8 a1 = *(const bf16x8*)&src264[(16 + lr)*264 + kt*32 + quad*8];
            bf16x8 a2 = *(const bf16x8*)&src264[(32 + lr)*264 + kt*32 + quad*8];
            bf16x8 b0 = *(const bf16x8*)&P[((size_t)(ntA*8 + kt)*64 + lane)*8];
            bf16x8 b1 = *(const bf16x8*)&P[((size_t)((ntA+1)*8 + kt)*64 + lane)*8];
            acc[0][0] = MFMA(a0, b0, acc[0][0], 0,0,0);
            acc[0][1] = MFMA(a1, b0, acc[0][1], 0,0,0);
            acc[0][2] = MFMA(a2, b0, acc[0][2], 0,0,0);
            acc[1][0] = MFMA(a0, b1, acc[1][0], 0,0,0);
            acc[1][1] = MFMA(a1, b1, acc[1][1], 0,0,0);
            acc[1][2] = MFMA(a2, b1, acc[1][2], 0,0,0);
        }
        #pragma unroll
        for (int i = 0; i < 2; ++i) {
            const int col = (ntA + i)*16 + lr;
            #pragma unroll
            for (int m = 0; m < 3; ++m)
                #pragma unroll
                for (int r = 0; r < 4; ++r) {
                    const int row = m*16 + quad*4 + r;
                    const float v = acc[i][m][r];
                    if (col < 256) {
                        if (row >= 2 && row < 34) qL[(row-2)*264 + col] = (__bf16)v;
                    } else if (row < 36) {
                        kvL[row*520 + (col - 256)] = (__bf16)v;
                    }
                }
        }
    }
}

// ---------------------------------------------------------------------------
// Attention (32 rows) from LDS qL/kvL -> cxL. (verified rounds 7/8/10/11/12)
// cxL MAY alias qL: each lane reads only the q chunk it later overwrites.
// ---------------------------------------------------------------------------
__device__ __forceinline__ void attn_lds(
    const __bf16* qL, const __bf16* kvL, __bf16* cxL, int s0, int tid)
{
    const int w = tid >> 6, lane = tid & 63, quad = lane >> 4, lr = lane & 15;
    const int r = 4*w + quad, s = s0 + r, ch0 = lr*16;

    float q[16];
    {
        bf16x8 q0 = *(const bf16x8*)&qL[r*264 + ch0];
        bf16x8 q1 = *(const bf16x8*)&qL[r*264 + ch0 + 8];
        #pragma unroll
        for (int i = 0; i < 8; ++i) { q[i] = (float)q0[i]; q[8+i] = (float)q1[i]; }
    }
    bf16x8 zv;
    #pragma unroll
    for (int i = 0; i < 8; ++i) zv[i] = (__bf16)0.f;

    const int offs[4] = {2, 1, -1, -2};
    float sc[4]; bf16x8 v0[4], v1[4];
    #pragma unroll
    for (int n = 0; n < 4; ++n) {
        const int s2 = s + offs[n];
        const bool ok = ((unsigned)s2 < 128u);
        const int lrow = r + offs[n] + 2;
        float p = 0.f;
        if (ok) {
            bf16x8 k0 = *(const bf16x8*)&kvL[lrow*520 + ch0];
            bf16x8 k1 = *(const bf16x8*)&kvL[lrow*520 + ch0 + 8];
            v0[n] = *(const bf16x8*)&kvL[lrow*520 + 256 + ch0];
            v1[n] = *(const bf16x8*)&kvL[lrow*520 + 256 + ch0 + 8];
            #pragma unroll
            for (int i = 0; i < 8; ++i) p += q[i]*(float)k0[i] + q[8+i]*(float)k1[i];
        } else { v0[n] = zv; v1[n] = zv; }
        p += __shfl_xor(p, 1);
        sc[n] = ok ? p * 0.17677669529663687f : 0.f;
    }
    const float mx = fmaxf(fmaxf(sc[0], sc[1]), fmaxf(sc[2], sc[3]));
    float se = 0.f, aw[4];
    #pragma unroll
    for (int n = 0; n < 4; ++n) { aw[n] = __expf(sc[n] - mx); se += aw[n]; }
    const float inv = 1.f / se;
    float cx[16];
    #pragma unroll
    for (int i = 0; i < 16; ++i) cx[i] = 0.f;
    #pragma unroll
    for (int n = 0; n < 4; ++n)
        #pragma unroll
        for (int i = 0; i < 8; ++i) {
            cx[i]   += aw[n]*(float)v0[n][i];
            cx[8+i] += aw[n]*(float)v1[n][i];
        }
    bf16x8 o0, o1;
    #pragma unroll
    for (int i = 0; i < 8; ++i) { o0[i] = (__bf16)(cx[i]*inv); o1[i] = (__bf16)(cx[8+i]*inv); }
    *(bf16x8*)&cxL[r*264 + ch0]     = o0;
    *(bf16x8*)&cxL[r*264 + ch0 + 8] = o1;
}

// ---------------------------------------------------------------------------
// step_k: ONE dispatch per scan step k (k = 0..NSTEP).
// blocks 0..255  : dec step td = k-1 (skip if k==0)
// blocks 256..511: enc step te = k   (skip if k==NSTEP)
// XCD-affinity remap: XCD = blockIdx % 8 (HW heuristic), so derive
//   qt  = (bid & 7) >> 1            -> each XCD touches ONE gate quarter
//   idx = ((bid >> 3) << 1)|(bid&1) -> (b, rg) bijection over remaining bits
// Per-XCD weight footprint: Pqkv_e+Pqkv_d+Pemb (shared) + 1/4 Pg_e + 1/4 Pg_d
// = 1.56 MB -> L2-resident. Correctness independent of the XCD mapping.
// LDS arena 73856 B -> 2 blocks/CU. Layout as rounds 11/12 (verified).
// ---------------------------------------------------------------------------
#define SM_A264   0
#define SM_R      19008
#define SM_CODE   35904
#define SM_Q      56448
#define SM_MISC   73344
#define SM_TOTAL  73856

__global__ __launch_bounds__(512, 4) void step_k(
    int k, const float* __restrict__ input,
    __bf16* __restrict__ P, __bf16* __restrict__ Q,
    const __bf16* __restrict__ Pqkv_e, const __bf16* __restrict__ Pqkv_d,
    const __bf16* __restrict__ Pemb,   const __bf16* __restrict__ Pg_e,
    const __bf16* __restrict__ Pg_d,
    const float* __restrict__ encWg, const float* __restrict__ encbg,
    const float* __restrict__ decbg, const float* __restrict__ embb,
    const float* __restrict__ outW,
    float* __restrict__ ec, float* __restrict__ outbuf)
{
    __shared__ __attribute__((aligned(16))) char SM[SM_TOTAL];

    const int tid  = threadIdx.x;
    const int w    = tid >> 6;
    const int lane = tid & 63;
    const int quad = lane >> 4, lr = lane & 15;
    const int mt = w >> 2, ct = w & 3;

    __bf16* aL  = (__bf16*)(SM + SM_A264);   // hL / dhL
    __bf16* kvL = (__bf16*)(SM + SM_R);
    __bf16* qL  = (__bf16*)(SM + SM_Q);
    __bf16* cxL = qL;                        // alias (safe, see attn_lds)

    if (blockIdx.x >= 256) {
        // ===================== ENC body (step te = k) =====================
        if (k >= NSTEP) return;
        const int bid = blockIdx.x - 256;
        const int qt  = (bid & 7) >> 1;                       // XCD-affine
        const int idx = ((bid >> 3) << 1) | (bid & 1);        // 0..63
        const int b = idx >> 2, rg = idx & 3;
        const int gbatch = b*128, s0 = rg*32, grow0 = gbatch + s0;
        const int ch = qt*64 + ct*16 + lr;
        float* xL = (float*)(SM + SM_MISC);

        // per-lane LSTM constants loaded early (before any barrier)
        float wx0[4], wx1[4], wx2[4], bgv[4];
        #pragma unroll
        for (int g = 0; g < 4; ++g) {
            const int c = g*256 + ch;
            wx0[g] = encWg[c]; wx1[g] = encWg[1024 + c]; wx2[g] = encWg[2048 + c];
            bgv[g] = encbg[c];
        }

        // stage eh_{k-1} halo rows (s0-2 .. s0+33) from P.enc
        for (int v = tid; v < 36*32; v += 512) {
            const int row = v >> 5, seg = v & 31, s = s0 - 2 + row;
            bf16x8 val;
            if ((unsigned)s < 128u)
                val = *(const bf16x8*)&P[(size_t)(gbatch + s)*512 + seg*8];
            else {
                #pragma unroll
                for (int i = 0; i < 8; ++i) val[i] = (__bf16)0.f;
            }
            *(bf16x8*)&aL[row*264 + seg*8] = val;
        }
        if (tid < 96) xL[tid] = input[((size_t)(b*Tz + k)*Sz + s0)*3 + tid];
        __syncthreads();

        qkv_lds(aL, Pqkv_e, qL, kvL, tid);
        __syncthreads();
        attn_lds(qL, kvL, cxL, s0, tid);
        __syncthreads();

        // gates (K=512: aL own rows | cxL) + LSTM
        f32x4 acc[4];
        #pragma unroll
        for (int g = 0; g < 4; ++g) acc[g] = f32x4{0.f,0.f,0.f,0.f};
        for (int kt = 0; kt < 16; ++kt) {
            const __bf16* As = (kt < 8)
                ? &aL [(2 + mt*16 + lr)*264 + kt*32 + quad*8]
                : &cxL[(mt*16 + lr)*264 + (kt-8)*32 + quad*8];
            bf16x8 af = *(const bf16x8*)As;
            #pragma unroll
            for (int g = 0; g < 4; ++g) {
                const int nt = qt*16 + ct*4 + g;
                bf16x8 bf = *(const bf16x8*)&Pg_e[((size_t)(nt*16 + kt)*64 + lane)*8];
                acc[g] = MFMA(af, bf, acc[g], 0,0,0);
            }
        }
        #pragma unroll
        for (int r = 0; r < 4; ++r) {
            const int row = mt*16 + quad*4 + r;
            const float x0 = xL[row*3], x1 = xL[row*3+1], x2 = xL[row*3+2];
            const float zi = acc[0][r] + x0*wx0[0] + x1*wx1[0] + x2*wx2[0] + bgv[0];
            const float zf = acc[1][r] + x0*wx0[1] + x1*wx1[1] + x2*wx2[1] + bgv[1];
            const float zg = acc[2][r] + x0*wx0[2] + x1*wx1[2] + x2*wx2[2] + bgv[2];
            const float zo = acc[3][r] + x0*wx0[3] + x1*wx1[3] + x2*wx2[3] + bgv[3];
            const size_t ei = (size_t)(grow0 + row)*256 + ch;
            const float cn = sigf(zf)*ec[ei] + sigf(zi)*tanhfast(zg);
            ec[ei] = cn;
            Q[(size_t)(grow0 + row)*512 + ch] = (__bf16)(sigf(zo)*tanhfast(cn));
        }
    } else {
        // ===================== DEC body (step td = k-1) =====================
        if (k < 1) return;
        const int td = k - 1;
        const int bid = blockIdx.x;
        const int qt  = (bid & 7) >> 1;                       // XCD-affine
        const int idx = ((bid >> 3) << 1) | (bid & 1);        // 0..63
        const int b = idx >> 2, rg = idx & 3;
        const int gbatch = b*128, s0 = rg*32, grow0 = gbatch + s0;
        const int ch = qt*64 + ct*16 + lr;
        __bf16* dhL   = aL;
        __bf16* ehtL  = (__bf16*)(SM + SM_R);      // dead after code GEMM
        __bf16* codeL = (__bf16*)(SM + SM_CODE);   // dead after gates code-part
        float* outredL = (float*)(SM + SM_MISC);

        // per-lane constants early
        float bgv[4];
        #pragma unroll
        for (int g = 0; g < 4; ++g) bgv[g] = decbg[g*256 + ch];
        const float ow = outW[ch];

        // stage eh_{td} own rows (P.enc) + dh_{td-1} halo (Q.dh)
        for (int v = tid; v < 32*32; v += 512) {
            const int row = v >> 5, seg = v & 31;
            *(bf16x8*)&ehtL[row*264 + seg*8] =
                *(const bf16x8*)&P[(size_t)(grow0 + row)*512 + seg*8];
        }
        for (int v = tid; v < 36*32; v += 512) {
            const int row = v >> 5, seg = v & 31, s = s0 - 2 + row;
            bf16x8 val;
            if ((unsigned)s < 128u)
                val = *(const bf16x8*)&Q[(size_t)(gbatch + s)*512 + 256 + seg*8];
            else {
                #pragma unroll
                for (int i = 0; i < 8; ++i) val[i] = (__bf16)0.f;
            }
            *(bf16x8*)&dhL[row*264 + seg*8] = val;
        }
        __syncthreads();

        // code = sig(eh_{td} @ embW + embb) -> codeL
        // (ehtL reads and codeL writes are DISJOINT LDS regions -> no extra sync)
        {
            f32x4 cacc[2][2];
            #pragma unroll
            for (int m = 0; m < 2; ++m)
                #pragma unroll
                for (int i = 0; i < 2; ++i) cacc[m][i] = f32x4{0.f,0.f,0.f,0.f};
            for (int kt = 0; kt < 8; ++kt) {
                bf16x8 a0 = *(const bf16x8*)&ehtL[(lr)*264      + kt*32 + quad*8];
                bf16x8 a1 = *(const bf16x8*)&ehtL[(16 + lr)*264 + kt*32 + quad*8];
                #pragma unroll
                for (int i = 0; i < 2; ++i) {
                    bf16x8 bf = *(const bf16x8*)&Pemb[((size_t)((2*w + i)*8 + kt)*64 + lane)*8];
                    cacc[0][i] = MFMA(a0, bf, cacc[0][i], 0,0,0);
                    cacc[1][i] = MFMA(a1, bf, cacc[1][i], 0,0,0);
                }
            }
            #pragma unroll
            for (int i = 0; i < 2; ++i) {
                const int col = (2*w + i)*16 + lr;
                const float bb = embb[col];
                #pragma unroll
                for (int m = 0; m < 2; ++m)
                    #pragma unroll
                    for (int r = 0; r < 4; ++r)
                        codeL[(m*16 + quad*4 + r)*264 + col] = (__bf16)sigf(cacc[m][i][r] + bb);
            }
        }
        __syncthreads();   // codeL visible to all waves

        // gates acc: code part FIRST (kt 0..7) so codeL dies before kvL overlay
        f32x4 acc[4];
        #pragma unroll
        for (int g = 0; g < 4; ++g) acc[g] = f32x4{0.f,0.f,0.f,0.f};
        for (int kt = 0; kt < 8; ++kt) {
            bf16x8 af = *(const bf16x8*)&codeL[(mt*16 + lr)*264 + kt*32 + quad*8];
            #pragma unroll
            for (int g = 0; g < 4; ++g) {
                const int nt = qt*16 + ct*4 + g;
                bf16x8 bf = *(const bf16x8*)&Pg_d[((size_t)(nt*24 + kt)*64 + lane)*8];
                acc[g] = MFMA(af, bf, acc[g], 0,0,0);
            }
        }
        __syncthreads();   // codeL/ehtL dead; kvL may now overwrite region R

        // dec qkv from dh_{td-1} halo (kvL overlays ehtL+codeL region)
        qkv_lds(dhL, Pqkv_d, qL, kvL, tid);
        __syncthreads();
        attn_lds(qL, kvL, cxL, s0, tid);
        __syncthreads();

        // gates rest (kt 8..23: dhL own | cxL) + LSTM + outproj
        for (int kt = 8; kt < 24; ++kt) {
            const __bf16* As = (kt < 16)
                ? &dhL[(2 + mt*16 + lr)*264 + (kt-8)*32 + quad*8]
                : &cxL[(mt*16 + lr)*264 + (kt-16)*32 + quad*8];
            bf16x8 af = *(const bf16x8*)As;
            #pragma unroll
            for (int g = 0; g < 4; ++g) {
                const int nt = qt*16 + ct*4 + g;
                bf16x8 bf = *(const bf16x8*)&Pg_d[((size_t)(nt*24 + kt)*64 + lane)*8];
                acc[g] = MFMA(af, bf, acc[g], 0,0,0);
            }
        }
        #pragma unroll
        for (int r = 0; r < 4; ++r) {
            const int row = mt*16 + quad*4 + r;
            const float zi = acc[0][r] + bgv[0];
            const float zf = acc[1][r] + bgv[1];
            const float zg = acc[2][r] + bgv[2];
            const float zo = acc[3][r] + bgv[3];
            const float c_old = (float)dhL[(2 + row)*264 + ch];
            const float cn = sigf(zf)*c_old + sigf(zi)*tanhfast(zg);
            const float h  = sigf(zo)*tanhfast(cn);
            P[(size_t)(grow0 + row)*512 + 256 + ch] = (__bf16)h;
            float pv = h * ow;
            pv += __shfl_xor(pv, 1); pv += __shfl_xor(pv, 2);
            pv += __shfl_xor(pv, 4); pv += __shfl_xor(pv, 8);
            if (lr == 0) outredL[row*4 + ct] = pv;
        }
        __syncthreads();
        if (tid < 32) {
            const float s4 = outredL[tid*4] + outredL[tid*4+1]
                           + outredL[tid*4+2] + outredL[tid*4+3];
            atomicAdd(&outbuf[(size_t)td*Mz + grow0 + tid], s4);
        }
    }
}

// ---------------------------------------------------------------------------
// Final assembly (unchanged, verified)
// ---------------------------------------------------------------------------
__global__ __launch_bounds__(256) void assemble_k(
    const float* __restrict__ outbuf, const float* __restrict__ input,
    const float* __restrict__ outb, float* __restrict__ out)
{
    const int idx = blockIdx.x*256 + threadIdx.x;
    const int NT = NSTEP - TPz;                 // 27
    if (idx >= Bz*NT*Sz) return;
    const int s  = idx & 127;
    const int bi = idx >> 7;
    const int i  = bi % NT;
    const int b  = bi / NT;
    const int t  = i + TPz;
    const float ob = outb[0];
    const float o  = outbuf[t*Mz + (b<<7) + s] + ob;
    const float In = (s == 0)
        ? input[((size_t)(b*Tz + t + 1)*Sz)*3 + 1]
        : outbuf[t*Mz + (b<<7) + s - 1] + ob;
    const float num = input[((size_t)(b*Tz + t)*Sz + s)*3 + 2] + In - o;
    const size_t base = ((size_t)(b*NT + i)*Sz + s)*3;
    out[base+0] = o;
    out[base+1] = In;
    out[base+2] = num;
}

// ---------------------------------------------------------------------------
extern "C" void kernel_launch(void* const* d_in, const int* in_sizes, int n_in,
                              void* d_out, int out_size, void* d_ws, size_t ws_size,
                              hipStream_t stream)
{
    const float* input = (const float*)d_in[0];
    const float* encWq = (const float*)d_in[1];
    const float* encWk = (const float*)d_in[2];
    const float* encWv = (const float*)d_in[3];
    const float* encWg = (const float*)d_in[4];
    const float* encbg = (const float*)d_in[5];
    const float* decWq = (const float*)d_in[6];
    const float* decWk = (const float*)d_in[7];
    const float* decWv = (const float*)d_in[8];
    const float* decWg = (const float*)d_in[9];
    const float* decbg = (const float*)d_in[10];
    const float* embW  = (const float*)d_in[11];
    const float* embb  = (const float*)d_in[12];
    const float* outW  = (const float*)d_in[13];
    const float* outb  = (const float*)d_in[14];

    char* ws = (char*)d_ws;
    size_t off = 0;
    auto alloc = [&](size_t bytes) -> void* {
        void* p = ws + off;
        off += (bytes + 255) & ~(size_t)255;
        return p;
    };
    __bf16* Pqkv_e = (__bf16*)alloc((size_t)768*256*2);
    __bf16* Pqkv_d = (__bf16*)alloc((size_t)768*256*2);
    __bf16* Pemb   = (__bf16*)alloc((size_t)256*256*2);
    __bf16* Pg_e   = (__bf16*)alloc((size_t)1024*512*2);
    __bf16* Pg_d   = (__bf16*)alloc((size_t)1024*768*2);
    __bf16* Xa     = (__bf16*)alloc((size_t)Mz*512*2);   // [ehb|dh] ping
    __bf16* Xb     = (__bf16*)alloc((size_t)Mz*512*2);   // pong
    float*  ec     = (float*) alloc((size_t)Mz*256*4);
    float*  outbuf = (float*) alloc((size_t)NSTEP*Mz*4);

    hipMemsetAsync(Xa, 0, (size_t)Mz*512*2, stream);
    hipMemsetAsync(ec, 0, (size_t)Mz*256*4, stream);
    hipMemsetAsync(outbuf, 0, (size_t)NSTEP*Mz*4, stream);

    prep3<<<6912, 256, 0, stream>>>(encWq, encWk, encWv, encWg,
                                    decWq, decWk, decWv, decWg, embW,
                                    Pqkv_e, Pqkv_d, Pemb, Pg_e, Pg_d);

    for (int k = 0; k <= NSTEP; ++k) {
        __bf16* P = (k & 1) ? Xb : Xa;
        __bf16* Q = (k & 1) ? Xa : Xb;
        step_k<<<512, 512, 0, stream>>>(k, input, P, Q,
                                        Pqkv_e, Pqkv_d, Pemb, Pg_e, Pg_d,
                                        encWg, encbg, decbg, embb, outW,
                                        ec, outbuf);
    }
    assemble_k<<<(Bz*(NSTEP-TPz)*Sz + 255)/256, 256, 0, stream>>>(
        outbuf, input, outb, (float*)d_out);
}

// Round 14
// 1287.728 us; speedup vs baseline: 1.0090x; 1.0051x over previous
//
#include <hip/hip_runtime.h>
#include <hip/hip_bf16.h>

// Problem constants
#define Bz 16
#define Tz 32
#define Sz 128
#define TPz 4
#define Mz (Bz*Sz)          // 2048 rows
#define NSTEP (Tz-1)        // 31

typedef __bf16 bf16x8 __attribute__((ext_vector_type(8)));
typedef float  f32x4  __attribute__((ext_vector_type(4)));

#define MFMA __builtin_amdgcn_mfma_f32_16x16x32_bf16

__device__ __forceinline__ float sigf(float x) { return 1.f/(1.f + __expf(-x)); }
// fast tanh: 1 - 2/(e^{2x}+1); exact at +-inf, ~1e-7 rel err
__device__ __forceinline__ float tanhfast(float x) { return 1.f - 2.f/(__expf(2.f*x) + 1.f); }

// ---------------------------------------------------------------------------
// prep3 (verified rounds 7/8/10-13): pack weights (fp32) into bf16 MFMA
// B-fragment order: P[((nt*KT + kt)*64 + lane)*8 + j] =
//        BT[nt*16 + (lane&15)][kt*32 + (lane>>4)*8 + j]
// ---------------------------------------------------------------------------
__global__ __launch_bounds__(256) void prep3(
    const float* __restrict__ encWq, const float* __restrict__ encWk,
    const float* __restrict__ encWv, const float* __restrict__ encWg,
    const float* __restrict__ decWq, const float* __restrict__ decWk,
    const float* __restrict__ decWv, const float* __restrict__ decWg,
    const float* __restrict__ embW,
    __bf16* __restrict__ Pqkv_e, __bf16* __restrict__ Pqkv_d,
    __bf16* __restrict__ Pemb,   __bf16* __restrict__ Pg_e,
    __bf16* __restrict__ Pg_d)
{
    int id = blockIdx.x * 256 + threadIdx.x;
    if (id < 768*256) {
        int f = id >> 9, e = id & 511, l = e >> 3, j = e & 7;
        int nt = f >> 3, kt = f & 7;
        int n = nt*16 + (l & 15), k = kt*32 + (l >> 4)*8 + j;
        float v = (n < 256) ? encWq[k*256 + n]
                : (n < 512) ? encWk[k*256 + (n-256)]
                            : encWv[k*256 + (n-512)];
        Pqkv_e[id] = (__bf16)v; return;
    }
    id -= 768*256;
    if (id < 768*256) {
        int f = id >> 9, e = id & 511, l = e >> 3, j = e & 7;
        int nt = f >> 3, kt = f & 7;
        int n = nt*16 + (l & 15), k = kt*32 + (l >> 4)*8 + j;
        float v = (n < 256) ? decWq[k*256 + n]
                : (n < 512) ? decWk[k*256 + (n-256)]
                            : decWv[k*256 + (n-512)];
        Pqkv_d[id] = (__bf16)v; return;
    }
    id -= 768*256;
    if (id < 256*256) {
        int f = id >> 9, e = id & 511, l = e >> 3, j = e & 7;
        int nt = f >> 3, kt = f & 7;
        int n = nt*16 + (l & 15), k = kt*32 + (l >> 4)*8 + j;
        Pemb[id] = (__bf16)embW[k*256 + n]; return;
    }
    id -= 256*256;
    if (id < 1024*512) {
        int f = id >> 9, e = id & 511, l = e >> 3, j = e & 7;
        int nt = f >> 4, kt = f & 15;
        int cht = nt >> 2, g = nt & 3;
        int ch = cht*16 + (l & 15), k = kt*32 + (l >> 4)*8 + j;
        Pg_e[id] = (__bf16)encWg[(size_t)(3 + k)*1024 + g*256 + ch]; return;
    }
    id -= 1024*512;
    if (id < 1024*768) {
        int f = id >> 9, e = id & 511, l = e >> 3, j = e & 7;
        int nt = f / 24, kt = f % 24;
        int cht = nt >> 2, g = nt & 3;
        int ch = cht*16 + (l & 15), k = kt*32 + (l >> 4)*8 + j;
        Pg_d[id] = (__bf16)decWg[(size_t)k*1024 + g*256 + ch]; return;
    }
}

// ---------------------------------------------------------------------------
// qkv GEMM from 36-row staged state (stride 264) -> qL (own 32 rows), kvL (36).
// kt loop fully unrolled: all 16 B loads independent -> deep pipelining.
// ---------------------------------------------------------------------------
__device__ __forceinline__ void qkv_lds(
    const __bf16* src264, const __bf16* __restrict__ P,
    __bf16* qL, __bf16* kvL, int tid)
{
    const int w = tid >> 6, lane = tid & 63, quad = (lane >> 4), lr = lane & 15;
    #pragma unroll
    for (int ng = 0; ng < 3; ++ng) {
        const int ntA = w*6 + ng*2;
        f32x4 acc[2][3];
        #pragma unroll
        for (int i = 0; i < 2; ++i)
            #pragma unroll
            for (int m = 0; m < 3; ++m) acc[i][m] = f32x4{0.f,0.f,0.f,0.f};
        #pragma unroll
        for (int kt = 0; kt < 8; ++kt) {
            bf16x8 a0 = *(const bf16x8*)&src264[(lr)*264      + kt*32 + quad*8];
            bf16x8 a1 = *(const bf16x8*)&src264[(16 + lr)*264 + kt*32 + quad*8];
            bf16x8 a2 = *(const bf16x8*)&src264[(32 + lr)*264 + kt*32 + quad*8];
            bf16x8 b0 = *(const bf16x8*)&P[((size_t)(ntA*8 + kt)*64 + lane)*8];
            bf16x8 b1 = *(const bf16x8*)&P[((size_t)((ntA+1)*8 + kt)*64 + lane)*8];
            acc[0][0] = MFMA(a0, b0, acc[0][0], 0,0,0);
            acc[0][1] = MFMA(a1, b0, acc[0][1], 0,0,0);
            acc[0][2] = MFMA(a2, b0, acc[0][2], 0,0,0);
            acc[1][0] = MFMA(a0, b1, acc[1][0], 0,0,0);
            acc[1][1] = MFMA(a1, b1, acc[1][1], 0,0,0);
            acc[1][2] = MFMA(a2, b1, acc[1][2], 0,0,0);
        }
        #pragma unroll
        for (int i = 0; i < 2; ++i) {
            const int col = (ntA + i)*16 + lr;
            #pragma unroll
            for (int m = 0; m < 3; ++m)
                #pragma unroll
                for (int r = 0; r < 4; ++r) {
                    const int row = m*16 + quad*4 + r;
                    const float v = acc[i][m][r];
                    if (col < 256) {
                        if (row >= 2 && row < 34) qL[(row-2)*264 + col] = (__bf16)v;
                    } else if (row < 36) {
                        kvL[row*520 + (col - 256)] = (__bf16)v;
                    }
                }
        }
    }
}

// ---------------------------------------------------------------------------
// Attention (32 rows) from LDS qL/kvL -> cxL. (verified rounds 7/8/10-13)
// cxL MAY alias qL: each lane reads only the q chunk it later overwrites.
// ---------------------------------------------------------------------------
__device__ __forceinline__ void attn_lds(
    const __bf16* qL, const __bf16* kvL, __bf16* cxL, int s0, int tid)
{
    const int w = tid >> 6, lane = tid & 63, quad = lane >> 4, lr = lane & 15;
    const int r = 4*w + quad, s = s0 + r, ch0 = lr*16;

    float q[16];
    {
        bf16x8 q0 = *(const bf16x8*)&qL[r*264 + ch0];
        bf16x8 q1 = *(const bf16x8*)&qL[r*264 + ch0 + 8];
        #pragma unroll
        for (int i = 0; i < 8; ++i) { q[i] = (float)q0[i]; q[8+i] = (float)q1[i]; }
    }
    bf16x8 zv;
    #pragma unroll
    for (int i = 0; i < 8; ++i) zv[i] = (__bf16)0.f;

    const int offs[4] = {2, 1, -1, -2};
    float sc[4]; bf16x8 v0[4], v1[4];
    #pragma unroll
    for (int n = 0; n < 4; ++n) {
        const int s2 = s + offs[n];
        const bool ok = ((unsigned)s2 < 128u);
        const int lrow = r + offs[n] + 2;
        float p = 0.f;
        if (ok) {
            bf16x8 k0 = *(const bf16x8*)&kvL[lrow*520 + ch0];
            bf16x8 k1 = *(const bf16x8*)&kvL[lrow*520 + ch0 + 8];
            v0[n] = *(const bf16x8*)&kvL[lrow*520 + 256 + ch0];
            v1[n] = *(const bf16x8*)&kvL[lrow*520 + 256 + ch0 + 8];
            #pragma unroll
            for (int i = 0; i < 8; ++i) p += q[i]*(float)k0[i] + q[8+i]*(float)k1[i];
        } else { v0[n] = zv; v1[n] = zv; }
        p += __shfl_xor(p, 1);
        sc[n] = ok ? p * 0.17677669529663687f : 0.f;
    }
    const float mx = fmaxf(fmaxf(sc[0], sc[1]), fmaxf(sc[2], sc[3]));
    float se = 0.f, aw[4];
    #pragma unroll
    for (int n = 0; n < 4; ++n) { aw[n] = __expf(sc[n] - mx); se += aw[n]; }
    const float inv = 1.f / se;
    float cx[16];
    #pragma unroll
    for (int i = 0; i < 16; ++i) cx[i] = 0.f;
    #pragma unroll
    for (int n = 0; n < 4; ++n)
        #pragma unroll
        for (int i = 0; i < 8; ++i) {
            cx[i]   += aw[n]*(float)v0[n][i];
            cx[8+i] += aw[n]*(float)v1[n][i];
        }
    bf16x8 o0, o1;
    #pragma unroll
    for (int i = 0; i < 8; ++i) { o0[i] = (__bf16)(cx[i]*inv); o1[i] = (__bf16)(cx[8+i]*inv); }
    *(bf16x8*)&cxL[r*264 + ch0]     = o0;
    *(bf16x8*)&cxL[r*264 + ch0 + 8] = o1;
}

// ---------------------------------------------------------------------------
// step_k: ONE dispatch per scan step k (k = 0..NSTEP).
// blocks 0..255  : dec step td = k-1 (skip if k==0)
// blocks 256..511: enc step te = k   (skip if k==NSTEP)
// XCD-affinity remap (round 13) + LDS arena 73856 B -> 2 blocks/CU (round 11).
// All MFMA kt-loops fully unrolled for load pipelining (this round).
// ---------------------------------------------------------------------------
#define SM_A264   0
#define SM_R      19008
#define SM_CODE   35904
#define SM_Q      56448
#define SM_MISC   73344
#define SM_TOTAL  73856

__global__ __launch_bounds__(512, 4) void step_k(
    int k, const float* __restrict__ input,
    __bf16* __restrict__ P, __bf16* __restrict__ Q,
    const __bf16* __restrict__ Pqkv_e, const __bf16* __restrict__ Pqkv_d,
    const __bf16* __restrict__ Pemb,   const __bf16* __restrict__ Pg_e,
    const __bf16* __restrict__ Pg_d,
    const float* __restrict__ encWg, const float* __restrict__ encbg,
    const float* __restrict__ decbg, const float* __restrict__ embb,
    const float* __restrict__ outW,
    float* __restrict__ ec, float* __restrict__ outbuf)
{
    __shared__ __attribute__((aligned(16))) char SM[SM_TOTAL];

    const int tid  = threadIdx.x;
    const int w    = tid >> 6;
    const int lane = tid & 63;
    const int quad = lane >> 4, lr = lane & 15;
    const int mt = w >> 2, ct = w & 3;

    __bf16* aL  = (__bf16*)(SM + SM_A264);   // hL / dhL
    __bf16* kvL = (__bf16*)(SM + SM_R);
    __bf16* qL  = (__bf16*)(SM + SM_Q);
    __bf16* cxL = qL;                        // alias (safe, see attn_lds)

    if (blockIdx.x >= 256) {
        // ===================== ENC body (step te = k) =====================
        if (k >= NSTEP) return;
        const int bid = blockIdx.x - 256;
        const int qt  = (bid & 7) >> 1;                       // XCD-affine
        const int idx = ((bid >> 3) << 1) | (bid & 1);        // 0..63
        const int b = idx >> 2, rg = idx & 3;
        const int gbatch = b*128, s0 = rg*32, grow0 = gbatch + s0;
        const int ch = qt*64 + ct*16 + lr;
        float* xL = (float*)(SM + SM_MISC);

        // per-lane LSTM constants loaded early (before any barrier)
        float wx0[4], wx1[4], wx2[4], bgv[4];
        #pragma unroll
        for (int g = 0; g < 4; ++g) {
            const int c = g*256 + ch;
            wx0[g] = encWg[c]; wx1[g] = encWg[1024 + c]; wx2[g] = encWg[2048 + c];
            bgv[g] = encbg[c];
        }

        // stage eh_{k-1} halo rows (s0-2 .. s0+33) from P.enc
        for (int v = tid; v < 36*32; v += 512) {
            const int row = v >> 5, seg = v & 31, s = s0 - 2 + row;
            bf16x8 val;
            if ((unsigned)s < 128u)
                val = *(const bf16x8*)&P[(size_t)(gbatch + s)*512 + seg*8];
            else {
                #pragma unroll
                for (int i = 0; i < 8; ++i) val[i] = (__bf16)0.f;
            }
            *(bf16x8*)&aL[row*264 + seg*8] = val;
        }
        if (tid < 96) xL[tid] = input[((size_t)(b*Tz + k)*Sz + s0)*3 + tid];
        __syncthreads();

        qkv_lds(aL, Pqkv_e, qL, kvL, tid);
        __syncthreads();
        attn_lds(qL, kvL, cxL, s0, tid);
        __syncthreads();

        // gates (K=512: aL own rows | cxL) + LSTM, fully unrolled
        f32x4 acc[4];
        #pragma unroll
        for (int g = 0; g < 4; ++g) acc[g] = f32x4{0.f,0.f,0.f,0.f};
        #pragma unroll
        for (int kt = 0; kt < 16; ++kt) {
            const __bf16* As = (kt < 8)
                ? &aL [(2 + mt*16 + lr)*264 + kt*32 + quad*8]
                : &cxL[(mt*16 + lr)*264 + (kt-8)*32 + quad*8];
            bf16x8 af = *(const bf16x8*)As;
            #pragma unroll
            for (int g = 0; g < 4; ++g) {
                const int nt = qt*16 + ct*4 + g;
                bf16x8 bf = *(const bf16x8*)&Pg_e[((size_t)(nt*16 + kt)*64 + lane)*8];
                acc[g] = MFMA(af, bf, acc[g], 0,0,0);
            }
        }
        #pragma unroll
        for (int r = 0; r < 4; ++r) {
            const int row = mt*16 + quad*4 + r;
            const float x0 = xL[row*3], x1 = xL[row*3+1], x2 = xL[row*3+2];
            const float zi = acc[0][r] + x0*wx0[0] + x1*wx1[0] + x2*wx2[0] + bgv[0];
            const float zf = acc[1][r] + x0*wx0[1] + x1*wx1[1] + x2*wx2[1] + bgv[1];
            const float zg = acc[2][r] + x0*wx0[2] + x1*wx1[2] + x2*wx2[2] + bgv[2];
            const float zo = acc[3][r] + x0*wx0[3] + x1*wx1[3] + x2*wx2[3] + bgv[3];
            const size_t ei = (size_t)(grow0 + row)*256 + ch;
            const float cn = sigf(zf)*ec[ei] + sigf(zi)*tanhfast(zg);
            ec[ei] = cn;
            Q[(size_t)(grow0 + row)*512 + ch] = (__bf16)(sigf(zo)*tanhfast(cn));
        }
    } else {
        // ===================== DEC body (step td = k-1) =====================
        if (k < 1) return;
        const int td = k - 1;
        const int bid = blockIdx.x;
        const int qt  = (bid & 7) >> 1;                       // XCD-affine
        const int idx = ((bid >> 3) << 1) | (bid & 1);        // 0..63
        const int b = idx >> 2, rg = idx & 3;
        const int gbatch = b*128, s0 = rg*32, grow0 = gbatch + s0;
        const int ch = qt*64 + ct*16 + lr;
        __bf16* dhL   = aL;
        __bf16* ehtL  = (__bf16*)(SM + SM_R);      // dead after code GEMM
        __bf16* codeL = (__bf16*)(SM + SM_CODE);   // dead after gates code-part
        float* outredL = (float*)(SM + SM_MISC);

        // per-lane constants early
        float bgv[4];
        #pragma unroll
        for (int g = 0; g < 4; ++g) bgv[g] = decbg[g*256 + ch];
        const float ow = outW[ch];

        // stage eh_{td} own rows (P.enc) + dh_{td-1} halo (Q.dh)
        for (int v = tid; v < 32*32; v += 512) {
            const int row = v >> 5, seg = v & 31;
            *(bf16x8*)&ehtL[row*264 + seg*8] =
                *(const bf16x8*)&P[(size_t)(grow0 + row)*512 + seg*8];
        }
        for (int v = tid; v < 36*32; v += 512) {
            const int row = v >> 5, seg = v & 31, s = s0 - 2 + row;
            bf16x8 val;
            if ((unsigned)s < 128u)
                val = *(const bf16x8*)&Q[(size_t)(gbatch + s)*512 + 256 + seg*8];
            else {
                #pragma unroll
                for (int i = 0; i < 8; ++i) val[i] = (__bf16)0.f;
            }
            *(bf16x8*)&dhL[row*264 + seg*8] = val;
        }
        __syncthreads();

        // code = sig(eh_{td} @ embW + embb) -> codeL, fully unrolled
        {
            f32x4 cacc[2][2];
            #pragma unroll
            for (int m = 0; m < 2; ++m)
                #pragma unroll
                for (int i = 0; i < 2; ++i) cacc[m][i] = f32x4{0.f,0.f,0.f,0.f};
            #pragma unroll
            for (int kt = 0; kt < 8; ++kt) {
                bf16x8 a0 = *(const bf16x8*)&ehtL[(lr)*264      + kt*32 + quad*8];
                bf16x8 a1 = *(const bf16x8*)&ehtL[(16 + lr)*264 + kt*32 + quad*8];
                #pragma unroll
                for (int i = 0; i < 2; ++i) {
                    bf16x8 bf = *(const bf16x8*)&Pemb[((size_t)((2*w + i)*8 + kt)*64 + lane)*8];
                    cacc[0][i] = MFMA(a0, bf, cacc[0][i], 0,0,0);
                    cacc[1][i] = MFMA(a1, bf, cacc[1][i], 0,0,0);
                }
            }
            #pragma unroll
            for (int i = 0; i < 2; ++i) {
                const int col = (2*w + i)*16 + lr;
                const float bb = embb[col];
                #pragma unroll
                for (int m = 0; m < 2; ++m)
                    #pragma unroll
                    for (int r = 0; r < 4; ++r)
                        codeL[(m*16 + quad*4 + r)*264 + col] = (__bf16)sigf(cacc[m][i][r] + bb);
            }
        }
        __syncthreads();   // codeL visible to all waves

        // gates acc: code part FIRST (kt 0..7), fully unrolled
        f32x4 acc[4];
        #pragma unroll
        for (int g = 0; g < 4; ++g) acc[g] = f32x4{0.f,0.f,0.f,0.f};
        #pragma unroll
        for (int kt = 0; kt < 8; ++kt) {
            bf16x8 af = *(const bf16x8*)&codeL[(mt*16 + lr)*264 + kt*32 + quad*8];
            #pragma unroll
            for (int g = 0; g < 4; ++g) {
                const int nt = qt*16 + ct*4 + g;
                bf16x8 bf = *(const bf16x8*)&Pg_d[((size_t)(nt*24 + kt)*64 + lane)*8];
                acc[g] = MFMA(af, bf, acc[g], 0,0,0);
            }
        }
        __syncthreads();   // codeL/ehtL dead; kvL may now overwrite region R

        // dec qkv from dh_{td-1} halo (kvL overlays ehtL+codeL region)
        qkv_lds(dhL, Pqkv_d, qL, kvL, tid);
        __syncthreads();
        attn_lds(qL, kvL, cxL, s0, tid);
        __syncthreads();

        // gates rest (kt 8..23: dhL own | cxL) + LSTM + outproj, unrolled
        #pragma unroll
        for (int kt = 8; kt < 24; ++kt) {
            const __bf16* As = (kt < 16)
                ? &dhL[(2 + mt*16 + lr)*264 + (kt-8)*32 + quad*8]
                : &cxL[(mt*16 + lr)*264 + (kt-16)*32 + quad*8];
            bf16x8 af = *(const bf16x8*)As;
            #pragma unroll
            for (int g = 0; g < 4; ++g) {
                const int nt = qt*16 + ct*4 + g;
                bf16x8 bf = *(const bf16x8*)&Pg_d[((size_t)(nt*24 + kt)*64 + lane)*8];
                acc[g] = MFMA(af, bf, acc[g], 0,0,0);
            }
        }
        #pragma unroll
        for (int r = 0; r < 4; ++r) {
            const int row = mt*16 + quad*4 + r;
            const float zi = acc[0][r] + bgv[0];
            const float zf = acc[1][r] + bgv[1];
            const float zg = acc[2][r] + bgv[2];
            const float zo = acc[3][r] + bgv[3];
            const float c_old = (float)dhL[(2 + row)*264 + ch];
            const float cn = sigf(zf)*c_old + sigf(zi)*tanhfast(zg);
            const float h  = sigf(zo)*tanhfast(cn);
            P[(size_t)(grow0 + row)*512 + 256 + ch] = (__bf16)h;
            float pv = h * ow;
            pv += __shfl_xor(pv, 1); pv += __shfl_xor(pv, 2);
            pv += __shfl_xor(pv, 4); pv += __shfl_xor(pv, 8);
            if (lr == 0) outredL[row*4 + ct] = pv;
        }
        __syncthreads();
        if (tid < 32) {
            const float s4 = outredL[tid*4] + outredL[tid*4+1]
                           + outredL[tid*4+2] + outredL[tid*4+3];
            atomicAdd(&outbuf[(size_t)td*Mz + grow0 + tid], s4);
        }
    }
}

// ---------------------------------------------------------------------------
// Final assembly (unchanged, verified)
// ---------------------------------------------------------------------------
__global__ __launch_bounds__(256) void assemble_k(
    const float* __restrict__ outbuf, const float* __restrict__ input,
    const float* __restrict__ outb, float* __restrict__ out)
{
    const int idx = blockIdx.x*256 + threadIdx.x;
    const int NT = NSTEP - TPz;                 // 27
    if (idx >= Bz*NT*Sz) return;
    const int s  = idx & 127;
    const int bi = idx >> 7;
    const int i  = bi % NT;
    const int b  = bi / NT;
    const int t  = i + TPz;
    const float ob = outb[0];
    const float o  = outbuf[t*Mz + (b<<7) + s] + ob;
    const float In = (s == 0)
        ? input[((size_t)(b*Tz + t + 1)*Sz)*3 + 1]
        : outbuf[t*Mz + (b<<7) + s - 1] + ob;
    const float num = input[((size_t)(b*Tz + t)*Sz + s)*3 + 2] + In - o;
    const size_t base = ((size_t)(b*NT + i)*Sz + s)*3;
    out[base+0] = o;
    out[base+1] = In;
    out[base+2] = num;
}

// ---------------------------------------------------------------------------
extern "C" void kernel_launch(void* const* d_in, const int* in_sizes, int n_in,
                              void* d_out, int out_size, void* d_ws, size_t ws_size,
                              hipStream_t stream)
{
    const float* input = (const float*)d_in[0];
    const float* encWq = (const float*)d_in[1];
    const float* encWk = (const float*)d_in[2];
    const float* encWv = (const float*)d_in[3];
    const float* encWg = (const float*)d_in[4];
    const float* encbg = (const float*)d_in[5];
    const float* decWq = (const float*)d_in[6];
    const float* decWk = (const float*)d_in[7];
    const float* decWv = (const float*)d_in[8];
    const float* decWg = (const float*)d_in[9];
    const float* decbg = (const float*)d_in[10];
    const float* embW  = (const float*)d_in[11];
    const float* embb  = (const float*)d_in[12];
    const float* outW  = (const float*)d_in[13];
    const float* outb  = (const float*)d_in[14];

    char* ws = (char*)d_ws;
    size_t off = 0;
    auto alloc = [&](size_t bytes) -> void* {
        void* p = ws + off;
        off += (bytes + 255) & ~(size_t)255;
        return p;
    };
    __bf16* Pqkv_e = (__bf16*)alloc((size_t)768*256*2);
    __bf16* Pqkv_d = (__bf16*)alloc((size_t)768*256*2);
    __bf16* Pemb   = (__bf16*)alloc((size_t)256*256*2);
    __bf16* Pg_e   = (__bf16*)alloc((size_t)1024*512*2);
    __bf16* Pg_d   = (__bf16*)alloc((size_t)1024*768*2);
    __bf16* Xa     = (__bf16*)alloc((size_t)Mz*512*2);   // [ehb|dh] ping
    __bf16* Xb     = (__bf16*)alloc((size_t)Mz*512*2);   // pong
    float*  ec     = (float*) alloc((size_t)Mz*256*4);
    float*  outbuf = (float*) alloc((size_t)NSTEP*Mz*4);

    hipMemsetAsync(Xa, 0, (size_t)Mz*512*2, stream);
    hipMemsetAsync(ec, 0, (size_t)Mz*256*4, stream);
    hipMemsetAsync(outbuf, 0, (size_t)NSTEP*Mz*4, stream);

    prep3<<<6912, 256, 0, stream>>>(encWq, encWk, encWv, encWg,
                                    decWq, decWk, decWv, decWg, embW,
                                    Pqkv_e, Pqkv_d, Pemb, Pg_e, Pg_d);

    for (int k = 0; k <= NSTEP; ++k) {
        __bf16* P = (k & 1) ? Xb : Xa;
        __bf16* Q = (k & 1) ? Xa : Xb;
        step_k<<<512, 512, 0, stream>>>(k, input, P, Q,
                                        Pqkv_e, Pqkv_d, Pemb, Pg_e, Pg_d,
                                        encWg, encbg, decbg, embb, outW,
                                        ec, outbuf);
    }
    assemble_k<<<(Bz*(NSTEP-TPz)*Sz + 255)/256, 256, 0, stream>>>(
        outbuf, input, outb, (float*)d_out);
}